// Round 6
// baseline (902.337 us; speedup 1.0000x reference)
//
#include <hip/hip_runtime.h>
#include <math.h>

#define CIN    64
#define OUTC   64
#define BOT    16
#define KK     9
#define HH     48
#define WW     48
#define LPIX   (HH*WW)
#define WSZ    9216
#define PSZ    1024
#define PREDCH 10304
#define GRPSZ  2576
#define BATCH  2
#define NPX    18          // 3 rows x 6 cols of pixels per block
#define PXS2   1172        // px-stride (ushorts) for P/Q buffers: 64*18 + 20 pad
                           // bank(b16 store, lanes=px) = 10*px mod 32 -> conflict-free
#define DBS    65

typedef __attribute__((ext_vector_type(8))) short short8v;
typedef __attribute__((ext_vector_type(4))) float float4v;

__device__ inline unsigned short f2bf(float f){
    unsigned u = __float_as_uint(f);
    return (unsigned short)((u + 0x7FFFu + ((u>>16)&1u)) >> 16);   // RNE
}

__global__ __launch_bounds__(256) void cvt_wp(const float* __restrict__ Wp,
                                              unsigned short* __restrict__ Wb) {
    const int n = PREDCH * 16;
    for (int i = blockIdx.x * 256 + threadIdx.x; i < n; i += gridDim.x * 256)
        Wb[i] = f2bf(Wp[i]);
}

// Block = 18 px (3x6), grid 256 (1/CU), 576 threads (9 waves).
// pred: D[ch][px] via mfma_16x16x32_bf16 (bias in k=16 slot).
// Per t: P_t staged to LDS as [px][c][d] (bf16, double-buffered);
// Y = P_t^T Q via MFMA (A=P from LDS b128, B=Q cached in regs);
// n_o = sum_c Y^2, dp_o = sum_c patch[c]*Y -> out += dp/sqrt(n).  No Gram/QGQ.
__global__ __launch_bounds__(576, 3) void dppc6(
    const float* __restrict__ x,
    const unsigned short* __restrict__ Wb,
    const float* __restrict__ bp,
    float* __restrict__ out)
{
    __shared__ float          xt[64 * 5 * 8];       // 10240 B  [c][r5][c8]
    __shared__ unsigned short S[2][NPX * PXS2];     // 84384 B  P_t dbuf; S[0] also stages Q
    __shared__ float          dynb[NPX * DBS];      //  4680 B

    const int tid  = threadIdx.x;
    const int wave = tid >> 6;
    const int lane = tid & 63;
    const int quad = lane >> 4;
    const int lrow = lane & 15;

    const int bi = blockIdx.x;
    const int b  = bi >> 7;
    const int r  = bi & 127;
    const int h0 = (r >> 3) * 3;
    const int w0 = (r & 7) * 6;

    // ---- xt load ----
    const float* xb = x + (size_t)b * CIN * LPIX;
    for (int i = tid; i < 64 * 5 * 8; i += 576) {
        const int c  = i / 40;
        const int rm = i - c * 40;
        const int hi = h0 - 1 + (rm >> 3);
        const int wi = w0 - 1 + (rm & 7);
        float v = 0.0f;
        if (hi >= 0 && hi < HH && wi >= 0 && wi < WW)
            v = xb[c * LPIX + hi * WW + wi];
        xt[i] = v;
    }
    __syncthreads();

    // ---- pred B-frags from center x (t-independent) ----
    short8v Bf[4][2];
    #pragma unroll
    for (int g = 0; g < 4; ++g) {
        #pragma unroll
        for (int nt = 0; nt < 2; ++nt) {
            const int px = nt * 16 + lrow;
            short8v f = (short8v)0;
            if (quad < 2 && px < NPX) {
                const int pr = px / 6, pc = px - 6 * (px / 6);
                #pragma unroll
                for (int j = 0; j < 8; ++j)
                    f[j] = (short)f2bf(xt[((g * 16 + quad * 8 + j) * 5 + pr + 1) * 8 + pc + 1]);
            }
            if (quad == 2 && px < NPX) f[0] = (short)0x3F80;   // bf16(1.0) bias slot
            Bf[g][nt] = f;
        }
    }

    // ---- Q + dyn_b phase (group 3), Q -> S[0] as [px][o*18+d] ----
    for (int u = wave; u < 68; u += 9) {
        const int ch0  = WSZ + u * 16;
        const int mych = ch0 + lrow;
        short8v a = (short8v)0;
        if (quad < 2)       a = *(const short8v*)(Wb + (size_t)mych * 16 + quad * 8);
        else if (quad == 2) a[0] = (short)f2bf(bp[mych]);
        #pragma unroll
        for (int nt = 0; nt < 2; ++nt) {
            float4v Dv = {0.f, 0.f, 0.f, 0.f};
            Dv = __builtin_amdgcn_mfma_f32_16x16x32_bf16(a, Bf[3][nt], Dv, 0, 0, 0);
            const int px = nt * 16 + lrow;
            if (px < NPX) {
                #pragma unroll
                for (int rr = 0; rr < 4; ++rr) {
                    const int ch = ch0 + quad * 4 + rr;
                    if (ch < WSZ + PSZ) {
                        const int i = ch - WSZ;
                        S[0][px * PXS2 + (i >> 4) * 18 + (i & 15)] = f2bf(Dv[rr]);
                    } else {
                        dynb[px * DBS + (ch - WSZ - PSZ)] = Dv[rr];
                    }
                }
            }
        }
    }
    __syncthreads();

    // ---- cache Q B-frags in registers: this wave's 2 pixels ----
    const int pxA = 2 * wave;          // 0..16
    const int pxB = 2 * wave + 1;      // 1..17
    short8v Bq[2][4];
    #pragma unroll
    for (int p = 0; p < 2; ++p) {
        const int px = 2 * wave + p;
        #pragma unroll
        for (int Nt = 0; Nt < 4; ++Nt) {
            short8v f = (short8v)0;
            if (quad < 2)
                f = *(const short8v*)&S[0][px * PXS2 + (Nt * 16 + lrow) * 18 + quad * 8];
            Bq[p][Nt] = f;
        }
    }
    __syncthreads();   // all waves done reading S[0] before pred(0) overwrites it

    float acc[2][4] = {};

    // ---- pred slice for tap t into buf ----
    #define PRED_SLICE(T, BUF)                                                        \
    for (int u = wave; u < 64; u += 9) {                                              \
        const int d  = u >> 2;                                                        \
        const int c0 = (u & 3) * 16;                                                  \
        const int ch0  = d * 576 + c0 * 9 + (T);                                      \
        const int mych = ch0 + 9 * lrow;                                              \
        short8v a = (short8v)0;                                                       \
        if (quad < 2)       a = *(const short8v*)(Wb + (size_t)mych * 16 + quad * 8); \
        else if (quad == 2) a[0] = (short)f2bf(bp[mych]);                             \
        const int g0  = ch0 / GRPSZ;                                                  \
        const int g1  = (ch0 + 135) / GRPSZ;                                          \
        const int myg = mych / GRPSZ;                                                 \
        _Pragma("unroll")                                                             \
        for (int nt = 0; nt < 2; ++nt) {                                              \
            float4v Dv = {0.f, 0.f, 0.f, 0.f};                                        \
            { short8v am = (myg == g0) ? a : (short8v)0;                              \
              Dv = __builtin_amdgcn_mfma_f32_16x16x32_bf16(am, Bf[g0][nt], Dv, 0,0,0);\
            }                                                                         \
            if (g1 != g0) {                                                           \
              short8v am = (myg == g1) ? a : (short8v)0;                              \
              Dv = __builtin_amdgcn_mfma_f32_16x16x32_bf16(am, Bf[g1][nt], Dv, 0,0,0);\
            }                                                                         \
            const int px = nt * 16 + lrow;                                            \
            if (px < NPX) {                                                           \
                _Pragma("unroll")                                                     \
                for (int rr = 0; rr < 4; ++rr)                                        \
                    S[BUF][px * PXS2 + (c0 + quad * 4 + rr) * 18 + d] = f2bf(Dv[rr]); \
            }                                                                         \
        }                                                                             \
    }

    PRED_SLICE(0, 0)
    __syncthreads();

    for (int t = 0; t < KK; ++t) {
        const int buf = t & 1;
        if (t < 8) { PRED_SLICE(t + 1, (t + 1) & 1) }

        // ---- Y = P_t^T Q for this wave's 2 pixels ----
        const int tr = t / 3, tc = t - 3 * (t / 3);
        #pragma unroll
        for (int p = 0; p < 2; ++p) {
            const int px = (p == 0) ? pxA : pxB;
            const int pr = px / 6, pc = px - 6 * (px / 6);

            short8v Ap[4];
            #pragma unroll
            for (int Mt = 0; Mt < 4; ++Mt) {
                short8v f = (short8v)0;
                if (quad < 2)
                    f = *(const short8v*)&S[buf][px * PXS2 + (Mt * 16 + lrow) * 18 + quad * 8];
                Ap[Mt] = f;
            }
            float pv[4][4];
            #pragma unroll
            for (int Mt = 0; Mt < 4; ++Mt)
                #pragma unroll
                for (int rr = 0; rr < 4; ++rr) {
                    const int c = Mt * 16 + quad * 4 + rr;
                    pv[Mt][rr] = xt[(c * 5 + pr + tr) * 8 + pc + tc];
                }

            #pragma unroll
            for (int Nt = 0; Nt < 4; ++Nt) {
                float nacc = 0.f, dpacc = 0.f;
                #pragma unroll
                for (int Mt = 0; Mt < 4; ++Mt) {
                    float4v Dv = {0.f, 0.f, 0.f, 0.f};
                    Dv = __builtin_amdgcn_mfma_f32_16x16x32_bf16(Ap[Mt], Bq[p][Nt], Dv, 0, 0, 0);
                    #pragma unroll
                    for (int rr = 0; rr < 4; ++rr) {
                        nacc  += Dv[rr] * Dv[rr];
                        dpacc += pv[Mt][rr] * Dv[rr];
                    }
                }
                nacc  += __shfl_xor(nacc, 16);  nacc  += __shfl_xor(nacc, 32);
                dpacc += __shfl_xor(dpacc, 16); dpacc += __shfl_xor(dpacc, 32);
                acc[p][Nt] += dpacc / fmaxf(sqrtf(fmaxf(nacc, 0.f)), 1e-12f);
            }
        }
        __syncthreads();
    }

    // ---- write out ----
    if (quad == 0) {
        #pragma unroll
        for (int p = 0; p < 2; ++p) {
            const int px = (p == 0) ? pxA : pxB;
            const int pr = px / 6, pc = px - 6 * (px / 6);
            const int l  = (h0 + pr) * WW + (w0 + pc);
            #pragma unroll
            for (int Nt = 0; Nt < 4; ++Nt) {
                const int o = Nt * 16 + lrow;
                out[((size_t)b * OUTC + o) * LPIX + l] = acc[p][Nt] + dynb[px * DBS + o];
            }
        }
    }
}

extern "C" void kernel_launch(void* const* d_in, const int* in_sizes, int n_in,
                              void* d_out, int out_size, void* d_ws, size_t ws_size,
                              hipStream_t stream) {
    const float* x  = (const float*)d_in[0];
    const float* Wp = (const float*)d_in[1];
    const float* bp = (const float*)d_in[2];
    float* out = (float*)d_out;
    unsigned short* Wb = (unsigned short*)d_ws;   // PREDCH*16 bf16 = 330 KB
    (void)in_sizes; (void)n_in; (void)out_size; (void)ws_size;

    hipLaunchKernelGGL(cvt_wp, dim3(160), dim3(256), 0, stream, Wp, Wb);
    hipLaunchKernelGGL(dppc6, dim3(BATCH * 128), dim3(576), 0, stream, x, Wb, bp, out);
}

// Round 7
// 153.318 us; speedup vs baseline: 5.8854x; 5.8854x over previous
//
#include <hip/hip_runtime.h>
#include <math.h>

#define CIN    64
#define OUTC   64
#define BOT    16
#define KK     9
#define HH     48
#define WW     48
#define LPIX   (HH*WW)
#define WSZ    9216
#define PSZ    1024
#define PREDCH 10304
#define GRPSZ  2576
#define BATCH  2
#define NPX    18          // 3 rows x 6 cols of pixels per block
#define PXS2   1172        // px-stride (ushorts): 64*18 + 20 pad (conflict-free)
#define DBS    65

typedef __attribute__((ext_vector_type(8))) short short8v;
typedef __attribute__((ext_vector_type(4))) float float4v;

__device__ inline unsigned short f2bf(float f){
    unsigned u = __float_as_uint(f);
    return (unsigned short)((u + 0x7FFFu + ((u>>16)&1u)) >> 16);   // RNE
}

__global__ __launch_bounds__(256) void cvt_wp(const float* __restrict__ Wp,
                                              unsigned short* __restrict__ Wb) {
    const int n = PREDCH * 16;
    for (int i = blockIdx.x * 256 + threadIdx.x; i < n; i += gridDim.x * 256)
        Wb[i] = f2bf(Wp[i]);
}

// Block = 18 px (3x6), grid 256 (1/CU), 576 threads (9 waves).
// pred: D[ch][px] via mfma_16x16x32_bf16 (bias in k=16 slot).
// Per t: P_t staged to LDS as [px][c][d] (bf16, double-buffered);
// Y = P_t^T Q via MFMA (A=P from LDS b128, B=Q cached in regs, STATIC indices only);
// n_o = sum_c Y^2, dp_o = sum_c patch[c]*Y -> out += dp/sqrt(n).
__global__ __launch_bounds__(576, 3) void dppc7(
    const float* __restrict__ x,
    const unsigned short* __restrict__ Wb,
    const float* __restrict__ bp,
    float* __restrict__ out)
{
    __shared__ float          xt[64 * 5 * 8];       // 10240 B  [c][r5][c8]
    __shared__ unsigned short S[2][NPX * PXS2];     // 84384 B  P_t dbuf; S[0] also stages Q
    __shared__ float          dynb[NPX * DBS];      //  4680 B

    const int tid  = threadIdx.x;
    const int wave = tid >> 6;
    const int lane = tid & 63;
    const int quad = lane >> 4;
    const int lrow = lane & 15;

    const int bi = blockIdx.x;
    const int b  = bi >> 7;
    const int r  = bi & 127;
    const int h0 = (r >> 3) * 3;
    const int w0 = (r & 7) * 6;

    // ---- xt load ----
    const float* xb = x + (size_t)b * CIN * LPIX;
    for (int i = tid; i < 64 * 5 * 8; i += 576) {
        const int c  = i / 40;
        const int rm = i - c * 40;
        const int hi = h0 - 1 + (rm >> 3);
        const int wi = w0 - 1 + (rm & 7);
        float v = 0.0f;
        if (hi >= 0 && hi < HH && wi >= 0 && wi < WW)
            v = xb[c * LPIX + hi * WW + wi];
        xt[i] = v;
    }
    __syncthreads();

    // ---- pred B-frags from center x (t-independent) ----
    short8v Bf[4][2];
    #pragma unroll
    for (int g = 0; g < 4; ++g) {
        #pragma unroll
        for (int nt = 0; nt < 2; ++nt) {
            const int px = nt * 16 + lrow;
            short8v f = (short8v)0;
            if (quad < 2 && px < NPX) {
                const int pr = px / 6, pc = px - 6 * (px / 6);
                #pragma unroll
                for (int j = 0; j < 8; ++j)
                    f[j] = (short)f2bf(xt[((g * 16 + quad * 8 + j) * 5 + pr + 1) * 8 + pc + 1]);
            }
            if (quad == 2 && px < NPX) f[0] = (short)0x3F80;   // bf16(1.0) bias slot
            Bf[g][nt] = f;
        }
    }

    // ---- Q + dyn_b phase (group 3), Q -> S[0] as [px][o*18+d] ----
    for (int u = wave; u < 68; u += 9) {
        const int ch0  = WSZ + u * 16;
        const int mych = ch0 + lrow;
        short8v a = (short8v)0;
        if (quad < 2)       a = *(const short8v*)(Wb + (size_t)mych * 16 + quad * 8);
        else if (quad == 2) a[0] = (short)f2bf(bp[mych]);
        #pragma unroll
        for (int nt = 0; nt < 2; ++nt) {
            float4v Dv = {0.f, 0.f, 0.f, 0.f};
            Dv = __builtin_amdgcn_mfma_f32_16x16x32_bf16(a, Bf[3][nt], Dv, 0, 0, 0);
            const int px = nt * 16 + lrow;
            if (px < NPX) {
                #pragma unroll
                for (int rr = 0; rr < 4; ++rr) {
                    const int ch = ch0 + quad * 4 + rr;
                    if (ch < WSZ + PSZ) {
                        const int i = ch - WSZ;
                        S[0][px * PXS2 + (i >> 4) * 18 + (i & 15)] = f2bf(Dv[rr]);
                    } else {
                        dynb[px * DBS + (ch - WSZ - PSZ)] = Dv[rr];
                    }
                }
            }
        }
    }
    __syncthreads();

    // ---- cache Q B-frags in registers: this wave's 2 pixels ----
    const int pxA = 2 * wave;          // 0..16
    const int pxB = 2 * wave + 1;      // 1..17
    short8v Bq[2][4];
    #pragma unroll
    for (int p = 0; p < 2; ++p) {
        const int px = 2 * wave + p;
        #pragma unroll
        for (int Nt = 0; Nt < 4; ++Nt) {
            short8v f = (short8v)0;
            if (quad < 2)
                f = *(const short8v*)&S[0][px * PXS2 + (Nt * 16 + lrow) * 18 + quad * 8];
            Bq[p][Nt] = f;
        }
    }
    __syncthreads();   // all waves done reading S[0] before pred(0) overwrites it

    float acc[2][4] = {};

    // ---- pred slice for tap t into buf (STATIC Bf indices via literal PASS) ----
    #define PASS(GG, NT)                                                              \
        { short8v am = (myg == (GG)) ? a : (short8v)0;                                \
          Dv = __builtin_amdgcn_mfma_f32_16x16x32_bf16(am, Bf[GG][NT], Dv, 0, 0, 0); }

    #define PRED_SLICE(T, BUF)                                                        \
    for (int u = wave; u < 64; u += 9) {                                              \
        const int d  = u >> 2;                                                        \
        const int c0 = (u & 3) * 16;                                                  \
        const int ch0  = d * 576 + c0 * 9 + (T);                                      \
        const int mych = ch0 + 9 * lrow;                                              \
        short8v a = (short8v)0;                                                       \
        if (quad < 2)       a = *(const short8v*)(Wb + (size_t)mych * 16 + quad * 8); \
        else if (quad == 2) a[0] = (short)f2bf(bp[mych]);                             \
        const int g0  = ch0 / GRPSZ;                                                  \
        const int g1  = (ch0 + 135) / GRPSZ;                                          \
        const int myg = mych / GRPSZ;                                                 \
        _Pragma("unroll")                                                             \
        for (int nt = 0; nt < 2; ++nt) {                                              \
            float4v Dv = {0.f, 0.f, 0.f, 0.f};                                        \
            if (g0 == 0)      { PASS(0, nt) if (g1 == 1) PASS(1, nt) }                \
            else if (g0 == 1) { PASS(1, nt) if (g1 == 2) PASS(2, nt) }                \
            else if (g0 == 2) { PASS(2, nt) if (g1 == 3) PASS(3, nt) }                \
            else              { PASS(3, nt) }                                         \
            const int px = nt * 16 + lrow;                                            \
            if (px < NPX) {                                                           \
                _Pragma("unroll")                                                     \
                for (int rr = 0; rr < 4; ++rr)                                        \
                    S[BUF][px * PXS2 + (c0 + quad * 4 + rr) * 18 + d] = f2bf(Dv[rr]); \
            }                                                                         \
        }                                                                             \
    }

    PRED_SLICE(0, 0)
    __syncthreads();

    for (int t = 0; t < KK; ++t) {
        const int buf = t & 1;
        if (t < 8) { PRED_SLICE(t + 1, (t + 1) & 1) }

        // ---- Y = P_t^T Q for this wave's 2 pixels ----
        const int tr = t / 3, tc = t - 3 * (t / 3);
        #pragma unroll
        for (int p = 0; p < 2; ++p) {
            const int px = (p == 0) ? pxA : pxB;
            const int pr = px / 6, pc = px - 6 * (px / 6);

            short8v Ap[4];
            #pragma unroll
            for (int Mt = 0; Mt < 4; ++Mt) {
                short8v f = (short8v)0;
                if (quad < 2)
                    f = *(const short8v*)&S[buf][px * PXS2 + (Mt * 16 + lrow) * 18 + quad * 8];
                Ap[Mt] = f;
            }
            float pv[4][4];
            #pragma unroll
            for (int Mt = 0; Mt < 4; ++Mt)
                #pragma unroll
                for (int rr = 0; rr < 4; ++rr) {
                    const int c = Mt * 16 + quad * 4 + rr;
                    pv[Mt][rr] = xt[(c * 5 + pr + tr) * 8 + pc + tc];
                }

            #pragma unroll
            for (int Nt = 0; Nt < 4; ++Nt) {
                float nacc = 0.f, dpacc = 0.f;
                #pragma unroll
                for (int Mt = 0; Mt < 4; ++Mt) {
                    float4v Dv = {0.f, 0.f, 0.f, 0.f};
                    Dv = __builtin_amdgcn_mfma_f32_16x16x32_bf16(Ap[Mt], Bq[p][Nt], Dv, 0, 0, 0);
                    #pragma unroll
                    for (int rr = 0; rr < 4; ++rr) {
                        nacc  += Dv[rr] * Dv[rr];
                        dpacc += pv[Mt][rr] * Dv[rr];
                    }
                }
                nacc  += __shfl_xor(nacc, 16);  nacc  += __shfl_xor(nacc, 32);
                dpacc += __shfl_xor(dpacc, 16); dpacc += __shfl_xor(dpacc, 32);
                acc[p][Nt] += dpacc / fmaxf(sqrtf(fmaxf(nacc, 0.f)), 1e-12f);
            }
        }
        __syncthreads();
    }

    // ---- write out ----
    if (quad == 0) {
        #pragma unroll
        for (int p = 0; p < 2; ++p) {
            const int px = (p == 0) ? pxA : pxB;
            const int pr = px / 6, pc = px - 6 * (px / 6);
            const int l  = (h0 + pr) * WW + (w0 + pc);
            #pragma unroll
            for (int Nt = 0; Nt < 4; ++Nt) {
                const int o = Nt * 16 + lrow;
                out[((size_t)b * OUTC + o) * LPIX + l] = acc[p][Nt] + dynb[px * DBS + o];
            }
        }
    }
}

extern "C" void kernel_launch(void* const* d_in, const int* in_sizes, int n_in,
                              void* d_out, int out_size, void* d_ws, size_t ws_size,
                              hipStream_t stream) {
    const float* x  = (const float*)d_in[0];
    const float* Wp = (const float*)d_in[1];
    const float* bp = (const float*)d_in[2];
    float* out = (float*)d_out;
    unsigned short* Wb = (unsigned short*)d_ws;   // PREDCH*16 bf16 = 330 KB
    (void)in_sizes; (void)n_in; (void)out_size; (void)ws_size;

    hipLaunchKernelGGL(cvt_wp, dim3(160), dim3(256), 0, stream, Wp, Wb);
    hipLaunchKernelGGL(dppc7, dim3(BATCH * 128), dim3(576), 0, stream, x, Wb, bp, out);
}